// Round 5
// baseline (264.214 us; speedup 1.0000x reference)
//
#include <hip/hip_runtime.h>

// Problem constants: N=64, B=32, L=127; out = (B,L,L,L) f32 = 262,193,024 B.
//
// R5 unified HW model (fits ALL prior datapoints):
//   write BW = resident_waves/CU / (cycles between stores per wave),
//   ceiling ~6.5 TB/s (0.66 dwordx4 stores/cy/CU needed); nt bypasses L2
//   write-combining (R1); one-shot blocks pay per-wg dispatch (R0).
//   - rocclr fill: 4 waves/CU but UNROLLED (~2-3 instr/store) -> 6.5 TB/s
//   - R4: 4 waves/CU, 7-instr loop -> 0.33 st/cy -> 3.3 TB/s  (matched ~101us)
//   - R3: 32 waves but n>0 blocks ran ~25 instr/store k-loop -> tail-bound
//   - R1: nt kills it despite 32 waves; R0: dispatch-bound.
// No prior attempt had BOTH high wave count AND unrolled low-overhead stores.
// R5: 2048 blocks (8/CU, 32 waves/CU), contiguous 128KB chunk per block,
// pure zero pass unrolled x8 (coalesced dwordx4 per store, int32 indexing),
// scatter fused off the hot path (stage1 LDS list scan, stage3 post-barrier
// atomics within own chunk only).
//
// Floor: poison ~160 (harness) + 262MB @ ~6 TB/s ~= 44 + eps  => ~210us.

constexpr int PN = 64;
constexpr int PB = 32;
constexpr int PL = 2 * PN - 1;                                // 127
constexpr int TOTAL_F  = PB * PL * PL * PL;                   // 65,548,256 < 2^31
constexpr int TOTAL_V4 = TOTAL_F / 4;                         // 16,387,064
constexpr int NPTS = PB * PN;                                 // 2048

constexpr int ZB = 256;                                       // threads/block
constexpr int ZGRID = 2048;                                   // 8 blocks/CU
constexpr int CH = (TOTAL_V4 + ZGRID - 1) / ZGRID;            // 8002 float4s
constexpr int UNROLL = 8;                                     // 8 stores/iter

typedef float v4f __attribute__((ext_vector_type(4)));

__global__ __launch_bounds__(ZB) void lattice_fused_kernel(
        const float* __restrict__ acids,
        const int*   __restrict__ idx,
        const int*   __restrict__ mask,
        float*       __restrict__ outf) {
    __shared__ int   s_cnt;
    __shared__ int   s_off[NPTS];
    __shared__ float s_val[NPTS];

    v4f* __restrict__ out = (v4f*)outf;
    const int tid = threadIdx.x;
    const int lo = blockIdx.x * CH;                           // first float4
    int hi = lo + CH;
    if (hi > TOTAL_V4) hi = TOTAL_V4;
    if (tid == 0) s_cnt = 0;
    __syncthreads();

    // Stage 1: scan the 2048 scatter points; keep this chunk's hits (~1 avg).
    // 40KB of input re-read by 2048 blocks -> L2-absorbed, negligible.
    const int elo = lo * 4, ehi = hi * 4;
    for (int p = tid; p < NPTS; p += ZB) {
        if (mask[p] != 0) {
            int b  = p >> 6;                                  // p / N
            int i0 = idx[3 * p + 0] + (PN - 1);
            int i1 = idx[3 * p + 1] + (PN - 1);
            int i2 = idx[3 * p + 2] + (PN - 1);
            int off = ((b * PL + i0) * PL + i1) * PL + i2;    // < 2^26
            if (off >= elo && off < ehi) {
                int slot = atomicAdd(&s_cnt, 1);              // LDS atomic
                s_off[slot] = off;
                s_val[slot] = acids[p];
            }
        }
    }

    // Stage 2: pure unrolled zero pass. Each store instruction is perfectly
    // coalesced (lanes consecutive); 8 stores per loop iteration amortize
    // index/branch overhead to ~2.4 instr/store. Plain stores (no nt).
    const v4f z = {0.f, 0.f, 0.f, 0.f};
    int t = lo + tid;
    constexpr int STEP = ZB * UNROLL;                         // 2048 float4s
    for (; t + (UNROLL - 1) * ZB < hi; t += STEP) {
#pragma unroll
        for (int u = 0; u < UNROLL; ++u)
            out[t + u * ZB] = z;
    }
    for (; t < hi; t += ZB)
        out[t] = z;

    // Stage 3: barrier drains this block's zero stores (s_waitcnt vmcnt(0)
    // before s_barrier); hits lie inside this block's chunk by construction,
    // so the atomics land on already-zeroed cells. Collisions handled by
    // device-scope atomicAdd.
    __syncthreads();
    const int n = s_cnt;
    for (int k = tid; k < n; k += ZB) {
        atomicAdd(outf + s_off[k], s_val[k]);
    }
}

extern "C" void kernel_launch(void* const* d_in, const int* in_sizes, int n_in,
                              void* d_out, int out_size, void* d_ws, size_t ws_size,
                              hipStream_t stream) {
    const float* acids = (const float*)d_in[0];   // (B,N) f32
    const int*   idx   = (const int*)  d_in[1];   // (B,N,3) i32
    const int*   mask  = (const int*)  d_in[2];   // (B,N) bool -> i32 per harness
    float* out = (float*)d_out;

    lattice_fused_kernel<<<ZGRID, ZB, 0, stream>>>(acids, idx, mask, out);
}

// Round 6
// 225.534 us; speedup vs baseline: 1.1715x; 1.1715x over previous
//
#include <hip/hip_runtime.h>

// Problem constants (from reference):
//   N = 64 (protein length), B = 32 (batch), L = 2N-1 = 127 (lattice side)
//   out = (B, L, L, L) float32 = 65,548,256 elems = 262,193,024 B (~262 MB)
//
// R6 = revert to R2 (session best, 223.6us), per R5's pre-committed fallback.
//
// Session evidence ledger:
//  - Harness poison fill (1.049 GB @ 6.5-6.6 TB/s, ~159us) sits INSIDE the
//    timed window every iteration: untouchable floor.
//  - Custom zero kernels cap at ~2.6-3.3 TB/s across the ENTIRE config space:
//    one-shot 64k blocks (R0 3.6), nt grid-stride 32w/CU (R1 2.6), chunked
//    32w/CU w/ per-v4 merge (R3 2.6), chunked 4w/CU (R4 3.3), chunked 32w/CU
//    unrolled x8 (R5 3.1). Shape-insensitive ~half of rocclr's 6.6 TB/s on
//    the same buffer -> memory-path cap (write-allocate suspected), not
//    issue-rate, not stream-count, not nt (nt is separately harmful).
//  - The ONLY >=6 TB/s write path reachable from kernel_launch is the rocclr
//    fill via hipMemsetAsync (stream-ordered, graph-capturable).
// Therefore: memset for the 262 MB zero + tiny scatter kernel for the 2048
// masked atomic adds. Structural floor: poison ~159 + zero 40-58 + scatter ~2
// + graph edges => ~220us. R2 measured 223.6.

constexpr int PN = 64;
constexpr int PB = 32;
constexpr int PL = 2 * PN - 1;  // 127

__global__ void lattice_scatter_kernel(const float* __restrict__ acids,
                                       const int*   __restrict__ idx,
                                       const int*   __restrict__ mask,
                                       float*       __restrict__ out) {
    int t = blockIdx.x * blockDim.x + threadIdx.x;   // 0 .. B*N-1
    if (t >= PB * PN) return;
    if (mask[t] == 0) return;        // masked-off acids scatter 0 -> no-op under add
    float v = acids[t];
    int b = t >> 6;                  // t / N  (N == 64)
    int i0 = idx[3 * t + 0] + (PN - 1);
    int i1 = idx[3 * t + 1] + (PN - 1);
    int i2 = idx[3 * t + 2] + (PN - 1);
    size_t off = ((((size_t)b * PL + i0) * PL) + i1) * PL + i2;
    atomicAdd(out + off, v);         // device-scope; handles index collisions
}

extern "C" void kernel_launch(void* const* d_in, const int* in_sizes, int n_in,
                              void* d_out, int out_size, void* d_ws, size_t ws_size,
                              hipStream_t stream) {
    const float* acids = (const float*)d_in[0];   // (B,N) f32
    const int*   idx   = (const int*)  d_in[1];   // (B,N,3) i32
    const int*   mask  = (const int*)  d_in[2];   // (B,N) bool -> i32 per harness
    float* out = (float*)d_out;

    // Zero the lattice via the rocclr fill path — the only demonstrated
    // >=6 TB/s writer on this chip (poison fills: 1.049 GB @ 6.6 TB/s).
    hipMemsetAsync(out, 0, (size_t)out_size, stream);

    // Scatter-add the <=2048 masked values (stream-ordered after the zero).
    constexpr int total = PB * PN;   // 2048
    lattice_scatter_kernel<<<(total + 255) / 256, 256, 0, stream>>>(acids, idx, mask, out);
}